// Round 5
// baseline (642.092 us; speedup 1.0000x reference)
//
#include <hip/hip_runtime.h>

// MoE top-1 layer, MI355X. N=8192 tokens, D=1024, F=4096, E=8.
// R8: gemm -> m201-class phase-interleaved 256x256 grouped GEMM.
//   8 waves (512 thr), BK=64, LDS 128KB (2 buf x [A:2 half][B:2 half] x
//   [128][64] bf16, R4-verified XOR-swizzled chunk layout, 0-conflict).
//   4 phases per K-tile: {ds_read quadrant frags | 1 half-tile GLDS
//   prefetch | barrier | lgkmcnt(0) | setprio(1) 16 MFMA setprio(0) |
//   barrier}. Counted vmcnt(4) once per K-tile (phase 4), vmcnt(0) only
//   at the pipeline tail. Stage ledger: A-halves of buf b last read ph2,
//   restaged (t+2) ph3/ph4; B-halves last read ph3, restaged (t+1) at
//   next tile's ph1/ph2. vmcnt(4)@ph4 drains all of tile t+1.
// gate/wconv/route unchanged (BM=256 granularity in route via macro).

#define N_TOKENS 8192
#define D_MODEL  1024
#define D_FF     4096
#define N_EXPERTS 8

#define BM 256
#define BN 256
#define BK 64
#define NKT (D_MODEL / BK)                   // 16 k-iterations
#define MT_MAX (N_TOKENS / BM + N_EXPERTS)   // 40 m-tiles worst case
#define NTILES (D_FF / BN)                   // 16 n-tiles
#define GATE_BLOCKS (N_TOKENS / 4)           // 2048
#define WCONV_BLOCKS ((D_FF / 64) * (D_MODEL / 256) * N_EXPERTS)  // 2048

typedef float  floatx4 __attribute__((ext_vector_type(4)));
typedef short  short8  __attribute__((ext_vector_type(8)));

__device__ __forceinline__ unsigned short f2bf(float f) {
    union { float f; unsigned u; } a; a.f = f;
    return (unsigned short)((a.u + 0x7fffu + ((a.u >> 16) & 1u)) >> 16); // RNE
}

#define GLDS(gp, lp) __builtin_amdgcn_global_load_lds( \
    (const __attribute__((address_space(1))) unsigned int*)(const void*)(gp), \
    (__attribute__((address_space(3))) unsigned int*)(void*)(lp), 16, 0, 0)

#define MFMA16(a, b, c) __builtin_amdgcn_mfma_f32_16x16x32_bf16(a, b, c, 0, 0, 0)

// -------- gate: fp32 gemv -> top1, + x -> xb bf16 --------
__global__ __launch_bounds__(256) void gate_kernel(
    const float* __restrict__ x, const float* __restrict__ gw,
    const float* __restrict__ gb,
    unsigned short* __restrict__ xb, int* __restrict__ top1)
{
    int wave = threadIdx.x >> 6;
    int l    = threadIdx.x & 63;
    int n = blockIdx.x * 4 + wave;
    const float4* xr = (const float4*)(x + (size_t)n * D_MODEL);
    float acc[N_EXPERTS];
#pragma unroll
    for (int e = 0; e < N_EXPERTS; ++e) acc[e] = 0.f;
#pragma unroll
    for (int j = 0; j < 4; ++j) {
        int d4 = j * 64 + l;
        float4 v = xr[d4];
        float vv[4] = { v.x, v.y, v.z, v.w };
#pragma unroll
        for (int t = 0; t < 4; ++t) {
            const float4* g = (const float4*)(gw + (size_t)(d4 * 4 + t) * N_EXPERTS);
            float4 g0 = g[0], g1 = g[1];
            acc[0] += vv[t] * g0.x; acc[1] += vv[t] * g0.y;
            acc[2] += vv[t] * g0.z; acc[3] += vv[t] * g0.w;
            acc[4] += vv[t] * g1.x; acc[5] += vv[t] * g1.y;
            acc[6] += vv[t] * g1.z; acc[7] += vv[t] * g1.w;
        }
        union { unsigned short us[4]; uint2 u; } pk;
        pk.us[0] = f2bf(v.x); pk.us[1] = f2bf(v.y);
        pk.us[2] = f2bf(v.z); pk.us[3] = f2bf(v.w);
        ((uint2*)(xb + (size_t)n * D_MODEL))[d4] = pk.u;
    }
#pragma unroll
    for (int e = 0; e < N_EXPERTS; ++e)
        for (int off = 32; off > 0; off >>= 1)
            acc[e] += __shfl_down(acc[e], off);
    if (l == 0) {
        float best = acc[0] + gb[0]; int be = 0;
#pragma unroll
        for (int e = 1; e < N_EXPERTS; ++e) {
            float v = acc[e] + gb[e];
            if (v > best) { best = v; be = e; }
        }
        top1[n] = be;
    }
}

// -------- wconv: ew f32 [E][D][F] -> wt bf16 [E][F][D], 64f x 256d tiles --------
#define WST2 260
__global__ __launch_bounds__(256) void wconv_kernel(
    const float* __restrict__ ew, unsigned short* __restrict__ wt)
{
    __shared__ unsigned short tt[64 * WST2];   // 33.3 KB
    int b  = blockIdx.x;
    int f0 = (b & 63) * 64;                    // 64 f-tiles
    int d0 = ((b >> 6) & 3) * 256;             // 4 d-tiles
    int e  = b >> 8;                           // 8 experts
    int t  = threadIdx.x;
    const float* we = ew + (size_t)e * D_MODEL * D_FF + (size_t)d0 * D_FF + f0;
    int fg = (t & 15) * 4;                     // f-offset 0..60
    int dg = (t >> 4) * 16;                    // d-offset 0..240
    unsigned short v[4][16];
#pragma unroll
    for (int j = 0; j < 16; ++j) {
        float4 r = *(const float4*)(we + (size_t)(dg + j) * D_FF + fg);
        v[0][j] = f2bf(r.x); v[1][j] = f2bf(r.y);
        v[2][j] = f2bf(r.z); v[3][j] = f2bf(r.w);
    }
#pragma unroll
    for (int i = 0; i < 4; ++i) {
#pragma unroll
        for (int p = 0; p < 4; ++p) {
            union { unsigned short us[4]; uint2 u; } pk;
            pk.us[0] = v[i][p*4+0]; pk.us[1] = v[i][p*4+1];
            pk.us[2] = v[i][p*4+2]; pk.us[3] = v[i][p*4+3];
            *(uint2*)&tt[(size_t)(fg + i) * WST2 + dg + p * 4] = pk.u;
        }
    }
    __syncthreads();
    unsigned short* wte = wt + (size_t)e * D_FF * D_MODEL + (size_t)f0 * D_MODEL + d0;
    int fr = t >> 5;                           // 0..7
    int cr = (t & 31) * 8;                     // d-chunk 0..248
#pragma unroll
    for (int p = 0; p < 8; ++p) {
        int f = fr + p * 8;
        uint2 a = *(const uint2*)&tt[(size_t)f * WST2 + cr];
        uint2 c = *(const uint2*)&tt[(size_t)f * WST2 + cr + 4];
        uint4 o; o.x = a.x; o.y = a.y; o.z = c.x; o.w = c.y;
        *(uint4*)(wte + (size_t)f * D_MODEL + cr) = o;
    }
}

// -------- route: single block, histogram + scan + order-preserving scatter --------
__global__ __launch_bounds__(1024) void route_kernel(
    const int* __restrict__ top1, int* __restrict__ tile_expert, int* __restrict__ list)
{
    __shared__ int wtot[16][N_EXPERTS];
    __shared__ int wbase[16][N_EXPERTS];
    __shared__ int pofs[N_EXPERTS];
    int t = threadIdx.x, wv = t >> 6, l = t & 63;

    for (int i = t; i < MT_MAX * BM; i += 1024) list[i] = -1;

    int e8[8];
    const int4* tp = (const int4*)(top1 + t * 8);
    int4 a = tp[0], b = tp[1];
    e8[0] = a.x; e8[1] = a.y; e8[2] = a.z; e8[3] = a.w;
    e8[4] = b.x; e8[5] = b.y; e8[6] = b.z; e8[7] = b.w;
    int c[N_EXPERTS], s[N_EXPERTS];
#pragma unroll
    for (int e = 0; e < N_EXPERTS; ++e) c[e] = 0;
#pragma unroll
    for (int j = 0; j < 8; ++j) c[e8[j]]++;
#pragma unroll
    for (int e = 0; e < N_EXPERTS; ++e) s[e] = c[e];
    for (int off = 1; off < 64; off <<= 1) {
#pragma unroll
        for (int e = 0; e < N_EXPERTS; ++e) {
            int v = __shfl_up(s[e], off);
            if (l >= off) s[e] += v;
        }
    }
    if (l == 63)
#pragma unroll
        for (int e = 0; e < N_EXPERTS; ++e) wtot[wv][e] = s[e];
    __syncthreads();
    if (t == 0) {
        int cnt[N_EXPERTS];
        for (int e = 0; e < N_EXPERTS; ++e) {
            cnt[e] = 0;
            for (int w = 0; w < 16; ++w) { wbase[w][e] = cnt[e]; cnt[e] += wtot[w][e]; }
        }
        int off = 0;
        for (int e = 0; e < N_EXPERTS; ++e) {
            pofs[e] = off;
            int ntl = (cnt[e] + BM - 1) / BM;
            for (int k = 0; k < ntl; ++k) tile_expert[off / BM + k] = e;
            off += ntl * BM;
        }
        for (int k = off / BM; k < MT_MAX; ++k) tile_expert[k] = -1;
    }
    __syncthreads();
    int base[N_EXPERTS];
#pragma unroll
    for (int e = 0; e < N_EXPERTS; ++e) base[e] = pofs[e] + wbase[wv][e] + s[e] - c[e];
#pragma unroll
    for (int j = 0; j < 8; ++j) {
        int e = e8[j];
        list[base[e]++] = t * 8 + j;
    }
}

// -------- grouped GEMM: 256x256, 8 waves, 4-phase interleave, counted vmcnt --------
// Per phase: MFMA quadrant QUAD(AF,BF,MO,NO) = 4m x 2n frags x 2 k-steps = 16 MFMA.
#define QUAD(AF, BF, MO, NO)                                                   \
    __builtin_amdgcn_s_setprio(1);                                             \
    _Pragma("unroll")                                                          \
    for (int mi = 0; mi < 4; ++mi) {                                           \
        _Pragma("unroll")                                                      \
        for (int ni = 0; ni < 2; ++ni) {                                       \
            acc[(MO)+mi][(NO)+ni] = MFMA16(AF[mi][0], BF[ni][0], acc[(MO)+mi][(NO)+ni]); \
            acc[(MO)+mi][(NO)+ni] = MFMA16(AF[mi][1], BF[ni][1], acc[(MO)+mi][(NO)+ni]); \
        }                                                                      \
    }                                                                          \
    __builtin_amdgcn_s_setprio(0);

__global__ __launch_bounds__(512, 2) void gemm_kernel(
    const unsigned short* __restrict__ xb,   // [N][D] bf16
    const unsigned short* __restrict__ wt,   // [E][F][D] bf16
    const float* __restrict__ eb,            // [E][F]
    const int* __restrict__ tile_expert,
    const int* __restrict__ list,
    float* __restrict__ out)                 // [N][F]
{
    int bid = blockIdx.x;
    int xcd = bid & 7, j = bid >> 3;         // j 0..79
    int mt  = j >> 1;                        // 0..39
    int nt  = (xcd << 1) | (j & 1);          // each XCD owns 2 n-columns
    int e = tile_expert[mt];
    if (e < 0) return;
    int n0 = nt * BN;

    // half-tiles: [128 rows][64 k] bf16, R4-verified swizzle (0 conflicts):
    // chunk slot s holds (row = s>>3, c8 = (s&7)^(row&7)); 16B chunks.
    __shared__ unsigned short As[2][2][128 * BK];   // 64 KB
    __shared__ unsigned short Bs[2][2][128 * BK];   // 64 KB
    __shared__ int toks[BM];

    int tid = threadIdx.x;
    int lane = tid & 63, wave = tid >> 6;           // wave 0..7
    if (tid < BM) toks[tid] = list[mt * BM + tid];
    __syncthreads();

    // staging sources: per (half h, i): chunk s = i*512 + wave*64 + lane.
    // 2 GLDS per thread per half-stage (1024 chunks / 512 threads).
    int aoff[2][2], boff[2][2];
    const unsigned short* wbp = wt + (size_t)e * D_FF * D_MODEL;
#pragma unroll
    for (int h = 0; h < 2; ++h)
#pragma unroll
        for (int i = 0; i < 2; ++i) {
            int s = i * 512 + wave * 64 + lane;
            int row = s >> 3, c8 = (s & 7) ^ (row & 7);
            int ta = toks[h * 128 + row]; if (ta < 0) ta = 0;
            aoff[h][i] = ta * D_MODEL + c8 * 8;
            boff[h][i] = (n0 + h * 128 + row) * D_MODEL + c8 * 8;
        }

    auto stageA = [&](int b, int h, int kt) {
        unsigned short* dst = &As[b][h][0];
#pragma unroll
        for (int i = 0; i < 2; ++i)
            GLDS(xb + (size_t)aoff[h][i] + kt * BK, dst + (i * 512 + wave * 64) * 8);
    };
    auto stageB = [&](int b, int h, int kt) {
        unsigned short* dst = &Bs[b][h][0];
#pragma unroll
        for (int i = 0; i < 2; ++i)
            GLDS(wbp + (size_t)boff[h][i] + kt * BK, dst + (i * 512 + wave * 64) * 8);
    };

    floatx4 acc[8][4];
#pragma unroll
    for (int mi = 0; mi < 8; ++mi)
#pragma unroll
        for (int ni = 0; ni < 4; ++ni)
            acc[mi][ni] = (floatx4){0.f, 0.f, 0.f, 0.f};

    // wave -> output subtile: wr in {0,1} picks A-half; wc in 0..3, B-half = wc>>1.
    int wr = wave >> 2, wc = wave & 3;
    int q = lane >> 4, r = lane & 15;
    int cq0 = ((0 * 4 + q) ^ (r & 7)) * 8;          // k-step 0 chunk (swizzled)
    int cq1 = ((1 * 4 + q) ^ (r & 7)) * 8;          // k-step 1 chunk
    int arow[8], brow[4];
#pragma unroll
    for (int i = 0; i < 8; ++i) arow[i] = (i * 16 + r) * BK;
#pragma unroll
    for (int i = 0; i < 4; ++i) brow[i] = ((wc & 1) * 64 + i * 16 + r) * BK;
    const unsigned short* Abase[2] = { &As[0][wr][0], &As[1][wr][0] };
    const unsigned short* Bbase[2] = { &Bs[0][wc >> 1][0], &Bs[1][wc >> 1][0] };

    // prologue: T0 fully + T1 A-halves in flight; vmcnt(4) -> T0 landed.
    stageA(0, 0, 0); stageA(0, 1, 0); stageB(0, 0, 0); stageB(0, 1, 0);
    stageA(1, 0, 1); stageA(1, 1, 1);
    asm volatile("s_waitcnt vmcnt(4)" ::: "memory");
    __builtin_amdgcn_s_barrier();
    __builtin_amdgcn_sched_barrier(0);

    short8 af0[4][2], af1[4][2], bf0[2][2], bf1[2][2];

    for (int kt = 0; kt < NKT; ++kt) {
        int b = kt & 1;
        const unsigned short* A = Abase[b];
        const unsigned short* B = Bbase[b];

        // ---- phase 1: read af0 (8) + bf0 (4); stage B-half0(T+1); Q(0,0)
#pragma unroll
        for (int mi = 0; mi < 4; ++mi) {
            af0[mi][0] = *(const short8*)&A[arow[mi] + cq0];
            af0[mi][1] = *(const short8*)&A[arow[mi] + cq1];
        }
#pragma unroll
        for (int ni = 0; ni < 2; ++ni) {
            bf0[ni][0] = *(const short8*)&B[brow[ni] + cq0];
            bf0[ni][1] = *(const short8*)&B[brow[ni] + cq1];
        }
        if (kt + 1 < NKT) stageB(b ^ 1, 0, kt + 1);
        __builtin_amdgcn_sched_barrier(0);
        __builtin_amdgcn_s_barrier();
        asm volatile("s_waitcnt lgkmcnt(0)" ::: "memory");
        __builtin_amdgcn_sched_barrier(0);
        QUAD(af0, bf0, 0, 0)
        __builtin_amdgcn_sched_barrier(0);
        __builtin_amdgcn_s_barrier();

        // ---- phase 2: read af1 (8); stage B-half1(T+1); Q(1,0)
#pragma unroll
        for (int mi = 0; mi < 4; ++mi) {
            af1[mi][0] = *(const short8*)&A[arow[4 + mi] + cq0];
            af1[mi][1] = *(const short8*)&A[arow[4 + mi] + cq1];
        }
        if (kt + 1 < NKT) stageB(b ^ 1, 1, kt + 1);
        __builtin_amdgcn_sched_barrier(0);
        __builtin_amdgcn_s_barrier();
        asm volatile("s_waitcnt lgkmcnt(0)" ::: "memory");
        __builtin_amdgcn_sched_barrier(0);
        QUAD(af1, bf0, 4, 0)
        __builtin_amdgcn_sched_barrier(0);
        __builtin_amdgcn_s_barrier();

        // ---- phase 3: read bf1 (4); stage A-half0(T+2, buf b: last A-read was ph2); Q(1,1)
#pragma unroll
        for (int ni = 0; ni < 2; ++ni) {
            bf1[ni][0] = *(const short8*)&B[brow[2 + ni] + cq0];
            bf1[ni][1] = *(const short8*)&B[brow[2 + ni] + cq1];
        }
        if (kt + 2 < NKT) stageA(b, 0, kt + 2);
        __builtin_amdgcn_sched_barrier(0);
        __builtin_amdgcn_s_barrier();
        asm volatile("s_waitcnt lgkmcnt(0)" ::: "memory");
        __builtin_amdgcn_sched_barrier(0);
        QUAD(af1, bf1, 4, 2)
        __builtin_amdgcn_sched_barrier(0);
        __builtin_amdgcn_s_barrier();

        // ---- phase 4: stage A-half1(T+2); counted vmcnt; Q(0,1)
        if (kt + 2 < NKT) {
            stageA(b, 1, kt + 2);
            // outstanding: B0,B1(T+1) + A0,A1(T+2); keep newest 4 -> T+1 landed
            asm volatile("s_waitcnt vmcnt(4)" ::: "memory");
        } else {
            // tail: A-stages absent; drain so B(T+1) is guaranteed landed
            asm volatile("s_waitcnt vmcnt(0)" ::: "memory");
        }
        __builtin_amdgcn_sched_barrier(0);
        __builtin_amdgcn_s_barrier();
        QUAD(af0, bf1, 0, 2)
        __builtin_amdgcn_sched_barrier(0);
        __builtin_amdgcn_s_barrier();
    }

    // epilogue: C/D layout col=lane&15, row=(lane>>4)*4+i  [m89-verified]
#pragma unroll
    for (int ni = 0; ni < 4; ++ni) {
        int f = n0 + wc * 64 + ni * 16 + r;
        float bias = eb[(size_t)e * D_FF + f];
#pragma unroll
        for (int mi = 0; mi < 8; ++mi) {
            int mbase = wr * 128 + mi * 16 + q * 4;
#pragma unroll
            for (int i = 0; i < 4; ++i) {
                int tok = toks[mbase + i];
                if (tok >= 0) out[(size_t)tok * D_FF + f] = acc[mi][ni][i] + bias;
            }
        }
    }
}

extern "C" void kernel_launch(void* const* d_in, const int* in_sizes, int n_in,
                              void* d_out, int out_size, void* d_ws, size_t ws_size,
                              hipStream_t stream) {
    const float* x  = (const float*)d_in[0];
    const float* gw = (const float*)d_in[1];
    const float* gb = (const float*)d_in[2];
    const float* ew = (const float*)d_in[3];
    const float* eb = (const float*)d_in[4];
    float* out = (float*)d_out;

    char* ws = (char*)d_ws;
    int* top1        = (int*)ws;                    // 32 KB
    int* tile_expert = (int*)(ws + 32768);          // 160 B
    int* list        = (int*)(ws + 36864);          // 40*256*4 = 40960 B
    unsigned short* xb = (unsigned short*)(ws + 131072);                          // 16.8 MB
    unsigned short* wt = (unsigned short*)(ws + 131072 + (size_t)N_TOKENS * D_MODEL * 2); // 67 MB

    hipLaunchKernelGGL(gate_kernel, dim3(GATE_BLOCKS), dim3(256), 0, stream,
                       x, gw, gb, xb, top1);
    hipLaunchKernelGGL(wconv_kernel, dim3(WCONV_BLOCKS), dim3(256), 0, stream,
                       ew, wt);
    hipLaunchKernelGGL(route_kernel, dim3(1), dim3(1024), 0, stream,
                       top1, tile_expert, list);
    hipLaunchKernelGGL(gemm_kernel, dim3(MT_MAX * NTILES), dim3(512), 0, stream,
                       xb, wt, eb, tile_expert, list, out);
}